// Round 4
// baseline (282.148 us; speedup 1.0000x reference)
//
#include <hip/hip_runtime.h>
#include <cstdint>
#include <math.h>

typedef unsigned short ushort_t;
typedef __bf16 v8bf __attribute__((ext_vector_type(8)));
typedef float v4f __attribute__((ext_vector_type(4)));

constexpr int B_SZ = 32, NQ = 2048, NK = 2048, DH = 128;
constexpr int BQ = 64, BK = 64;
constexpr int PLD = 88;  // P LDS row stride (176 B, 16B-aligned)
constexpr float SCALE = 0.08838834764831845f;  // 1/sqrt(128)
constexpr size_t KB_BYTES = (size_t)B_SZ * NK * DH * 2;  // 16,777,216

// Swizzled tile layouts (64-key tiles, bf16, 16 KB each, contiguous in global):
//  K tile:  elem (key,d)  at key*128 + ((d>>3) ^ (key&7))*8 + (d&7)
//  Vt tile: elem (d,key)  at d*64  + ((key>>3) ^ (d&7))*8 + (key&7)
// Both make every staging write / gather read / MFMA fragment read bank-uniform
// (8 lanes per 4-bank group per instruction — the wave64 optimum).

__device__ inline v8bf cvt8(const float* __restrict__ p) {
  float4 f0 = *reinterpret_cast<const float4*>(p);
  float4 f1 = *reinterpret_cast<const float4*>(p + 4);
  v8bf r;
  r[0] = (__bf16)f0.x; r[1] = (__bf16)f0.y; r[2] = (__bf16)f0.z; r[3] = (__bf16)f0.w;
  r[4] = (__bf16)f1.x; r[5] = (__bf16)f1.y; r[6] = (__bf16)f1.z; r[7] = (__bf16)f1.w;
  return r;
}
__device__ inline v8bf cvt8s(const float* __restrict__ p, float sc) {
  float4 f0 = *reinterpret_cast<const float4*>(p);
  float4 f1 = *reinterpret_cast<const float4*>(p + 4);
  v8bf r;
  r[0] = (__bf16)(f0.x * sc); r[1] = (__bf16)(f0.y * sc);
  r[2] = (__bf16)(f0.z * sc); r[3] = (__bf16)(f0.w * sc);
  r[4] = (__bf16)(f1.x * sc); r[5] = (__bf16)(f1.y * sc);
  r[6] = (__bf16)(f1.z * sc); r[7] = (__bf16)(f1.w * sc);
  return r;
}

// async global->LDS, 16 B per lane; lds dest = wave-uniform base + lane*16
__device__ inline void gl_lds16(const ushort_t* g, ushort_t* l) {
  __builtin_amdgcn_global_load_lds(
      (const __attribute__((address_space(1))) uint32_t*)g,
      (__attribute__((address_space(3))) uint32_t*)l, 16, 0, 0);
}

// ---------------- prepass: K fp32 -> bf16, tiled+swizzled ----------------
__global__ __launch_bounds__(256) void prep_k(const float* __restrict__ K,
                                              ushort_t* __restrict__ Kb) {
  const int b = blockIdx.y, kt = blockIdx.x, t = threadIdx.x;
  ushort_t* tile = Kb + ((size_t)(b * 32 + kt)) * (64 * 128);
  for (int c = 0; c < 4; ++c) {
    const int key = (t >> 4) + 16 * c, dg = t & 15;
    v8bf v = cvt8(K + ((size_t)(b * NK + kt * 64 + key)) * DH + dg * 8);
    // write bank = 4*((dg^(key&7))&7): dg spans 16/wave -> uniform, conflict-free
    *reinterpret_cast<v8bf*>(tile + key * 128 + (((dg ^ (key & 7)) & 15) << 3)) = v;
  }
}

// ---------------- prepass: V fp32 -> bf16 transpose, tiled+swizzled ----------------
__global__ __launch_bounds__(256) void prep_v(const float* __restrict__ V,
                                              ushort_t* __restrict__ Vt) {
  // staging swizzle S=key>>3: gather-read lanes have key>>3 = t&7 (varies) while
  // d>>3 is wave-constant -> banks uniform on BOTH write and gather. KLD=128, no pad.
  __shared__ __align__(16) ushort_t st[64 * 128];
  const int b = blockIdx.y, kt = blockIdx.x, t = threadIdx.x;
  for (int c = 0; c < 4; ++c) {
    const int key = (t >> 4) + 16 * c, dg = t & 15;
    v8bf v = cvt8(V + ((size_t)(b * NK + kt * 64 + key)) * DH + dg * 8);
    *reinterpret_cast<v8bf*>(&st[key * 128 + (((dg ^ (key >> 3)) & 15) << 3)]) = v;
  }
  __syncthreads();
  ushort_t* tile = Vt + ((size_t)(b * 32 + kt)) * (128 * 64);
  for (int c = 0; c < 4; ++c) {
    const int d = (t >> 3) + 32 * c, kg = t & 7;  // keys kg*8..kg*8+7 at fixed d
    const int sg = ((d >> 3) ^ kg) & 15;
    alignas(16) ushort_t tmp[8];
    for (int j = 0; j < 8; ++j) tmp[j] = st[(kg * 8 + j) * 128 + sg * 8 + (d & 7)];
    // Vt tile layout: d*64 + ((kg ^ (d&7))&7)*8 + j  (j = key&7, in order)
    *reinterpret_cast<uint4*>(tile + d * 64 + (((kg ^ (d & 7)) & 7) << 3)) =
        *reinterpret_cast<const uint4*>(tmp);
  }
}

// ---------------- flash attention ----------------
// grid: 1024 blocks 1D, b = blk&31 (round-robin for balance), qt = blk>>5
template <bool KSWZ>
__global__ __launch_bounds__(256, 3) void attn(const float* __restrict__ Q,
                                               const float* __restrict__ K32,
                                               const ushort_t* __restrict__ Kb,
                                               const ushort_t* __restrict__ Vt,
                                               const int* __restrict__ vsl,
                                               float* __restrict__ Out) {
  __shared__ __align__(16) ushort_t sK[64 * 128];     // swizzled K[key][d]
  __shared__ __align__(16) ushort_t sV[128 * 64];     // swizzled Vt[d][key]
  __shared__ __align__(16) ushort_t sP[4][16 * PLD];  // per-wave bf16 P[qrow][key]

  const int b = blockIdx.x & 31, qt = blockIdx.x >> 5;
  const int t = threadIdx.x;
  const int w = t >> 6, lane = t & 63, quad = lane >> 4, l16 = lane & 15;
  const int q0 = qt * BQ;
  const int valid = vsl[b];

  // Q (pre-scaled) fragments, register-resident: A[m=l16][k=quad*8+j+32kk]
  v8bf qf[4];
  {
    const float* qp = Q + ((size_t)(b * NQ + q0 + w * 16 + l16)) * DH + quad * 8;
    for (int kk = 0; kk < 4; ++kk) qf[kk] = cvt8s(qp + 32 * kk, SCALE);
  }

  v4f o[8];
  for (int nb = 0; nb < 8; ++nb) o[nb] = (v4f){0.f, 0.f, 0.f, 0.f};
  float m_i[4], l_i[4];
  for (int r = 0; r < 4; ++r) { m_i[r] = -INFINITY; l_i[r] = 0.f; }

  const int nt = (valid + BK - 1) / BK;  // exp underflow == skip masked tiles

  for (int tile = 0; tile < nt; ++tile) {
    const int k0 = tile * BK;
    // ---- stage K tile (16 KB) ----
    if (KSWZ) {
      const ushort_t* kt_g = Kb + ((size_t)(b * 32 + tile)) * (64 * 128);
      for (int c = 0; c < 4; ++c)
        gl_lds16(kt_g + (c * 2048 + t * 8), sK + (c * 2048 + (t >> 6) * 512));
    } else {
      for (int c = 0; c < 4; ++c) {
        const int key = (t >> 4) + 16 * c, dg = t & 15;
        v8bf v = cvt8(K32 + ((size_t)(b * NK + k0 + key)) * DH + dg * 8);
        *reinterpret_cast<v8bf*>(&sK[key * 128 + (((dg ^ (key & 7)) & 15) << 3)]) = v;
      }
    }
    // ---- stage Vt tile (16 KB, verbatim) ----
    {
      const ushort_t* vt_g = Vt + ((size_t)(b * 32 + tile)) * (128 * 64);
      for (int c = 0; c < 4; ++c)
        gl_lds16(vt_g + (c * 2048 + t * 8), sV + (c * 2048 + (t >> 6) * 512));
    }
    __syncthreads();

    // ---- S = Q K^T ----
    float s[4][4];
    for (int cb = 0; cb < 4; ++cb) {
      v4f acc = (v4f){0.f, 0.f, 0.f, 0.f};
      const int key = l16 + 16 * cb;
      for (int kk = 0; kk < 4; ++kk) {
        const int dg = quad + 4 * kk;
        v8bf kf = __builtin_bit_cast(
            v8bf, *reinterpret_cast<const uint4*>(
                      &sK[key * 128 + (((dg ^ (l16 & 7)) & 15) << 3)]));
        acc = __builtin_amdgcn_mfma_f32_16x16x32_bf16(qf[kk], kf, acc, 0, 0, 0);
      }
      if (k0 + BK <= valid) {
        for (int r = 0; r < 4; ++r) s[cb][r] = acc[r];
      } else {
        const bool okk = (k0 + cb * 16 + l16) < valid;
        for (int r = 0; r < 4; ++r) s[cb][r] = okk ? acc[r] : -1e30f;
      }
    }

    // ---- online softmax (q-row quad*4+r spans the quad's 16 lanes) ----
    float alpha[4];
    for (int r = 0; r < 4; ++r) {
      float v = fmaxf(fmaxf(s[0][r], s[1][r]), fmaxf(s[2][r], s[3][r]));
      v = fmaxf(v, __shfl_xor(v, 1));
      v = fmaxf(v, __shfl_xor(v, 2));
      v = fmaxf(v, __shfl_xor(v, 4));
      v = fmaxf(v, __shfl_xor(v, 8));
      const float mn = fmaxf(m_i[r], v);
      alpha[r] = __expf(m_i[r] - mn);
      m_i[r] = mn;
      float rs = 0.f;
      for (int cb = 0; cb < 4; ++cb) {
        const float p = __expf(s[cb][r] - mn);
        s[cb][r] = p;
        rs += p;
      }
      rs += __shfl_xor(rs, 1);
      rs += __shfl_xor(rs, 2);
      rs += __shfl_xor(rs, 4);
      rs += __shfl_xor(rs, 8);
      l_i[r] = l_i[r] * alpha[r] + rs;
    }

    // ---- P (C-layout) -> per-wave LDS row-major for A-frag reads ----
    ushort_t* sPw = sP[w];
    for (int cb = 0; cb < 4; ++cb)
      for (int r = 0; r < 4; ++r)
        sPw[(quad * 4 + r) * PLD + cb * 16 + l16] =
            __builtin_bit_cast(ushort_t, (__bf16)s[cb][r]);
    __builtin_amdgcn_wave_barrier();  // per-wave buffer: pin store->load order

    for (int nb = 0; nb < 8; ++nb)
      for (int r = 0; r < 4; ++r) o[nb][r] *= alpha[r];

    // ---- O += P V ----
    v8bf pf[2];
    for (int kb = 0; kb < 2; ++kb)
      pf[kb] = __builtin_bit_cast(
          v8bf, *reinterpret_cast<const uint4*>(&sPw[l16 * PLD + quad * 8 + 32 * kb]));
    for (int nb = 0; nb < 8; ++nb) {
      const int d = l16 + 16 * nb;
      for (int kb = 0; kb < 2; ++kb) {
        const int kg = quad + 4 * kb;
        v8bf vf = __builtin_bit_cast(
            v8bf, *reinterpret_cast<const uint4*>(
                      &sV[d * 64 + (((kg ^ (d & 7)) & 7) << 3)]));
        o[nb] = __builtin_amdgcn_mfma_f32_16x16x32_bf16(pf[kb], vf, o[nb], 0, 0, 0);
      }
    }
    __syncthreads();  // protect sK/sV before next tile's staging
  }

  // ---- epilogue ----
  for (int r = 0; r < 4; ++r) {
    const float inv = 1.0f / l_i[r];
    float* op = Out + ((size_t)(b * NQ + q0 + w * 16 + quad * 4 + r)) * DH + l16;
    for (int nb = 0; nb < 8; ++nb) op[nb * 16] = o[nb][r] * inv;
  }
}

extern "C" void kernel_launch(void* const* d_in, const int* in_sizes, int n_in,
                              void* d_out, int out_size, void* d_ws, size_t ws_size,
                              hipStream_t stream) {
  const float* Q = (const float*)d_in[0];
  const float* K = (const float*)d_in[1];
  const float* V = (const float*)d_in[2];
  const int* vsl = (const int*)d_in[3];
  float* Out = (float*)d_out;

  const bool big = ws_size >= 2 * KB_BYTES;  // Kb + Vt (33.6 MB)
  ushort_t* Kb = (ushort_t*)d_ws;
  ushort_t* Vt = big ? (ushort_t*)d_ws + KB_BYTES / 2 : (ushort_t*)d_ws;

  dim3 blk(256);
  prep_v<<<dim3(NK / 64, B_SZ), blk, 0, stream>>>(V, Vt);
  if (big) {
    prep_k<<<dim3(NK / 64, B_SZ), blk, 0, stream>>>(K, Kb);
    attn<true><<<dim3(B_SZ * NQ / BQ), blk, 0, stream>>>(Q, K, Kb, Vt, vsl, Out);
  } else {
    attn<false><<<dim3(B_SZ * NQ / BQ), blk, 0, stream>>>(Q, K, Kb, Vt, vsl, Out);
  }
}